// Round 11
// baseline (172.848 us; speedup 1.0000x reference)
//
#include <hip/hip_runtime.h>
#include <hip/hip_bf16.h>
#include <stdint.h>

// Problem constants
#define NROWS 4096
#define NCLS  97
#define EMB   768
#define KTOT  49152                 // EMB * 64
#define OUT_ELEMS (NROWS * NCLS)    // 397312
#define NK32  (KTOT / 32)           // 1536 k-chunks of 32
#define WT_BYTES ((size_t)NK32 * 128 * 64)   // 12,582,912 (Wt: [kc][c<128][32] bf16)

typedef __attribute__((ext_vector_type(8)))  short short8;
typedef __attribute__((ext_vector_type(4)))  float floatx4;
typedef __bf16 bf16x2 __attribute__((ext_vector_type(2)));
typedef __bf16 bf16x8 __attribute__((ext_vector_type(8)));

__device__ __forceinline__ uint32_t pkmul(uint32_t a, uint32_t b) {
  bf16x2 x = __builtin_bit_cast(bf16x2, a);
  bf16x2 y = __builtin_bit_cast(bf16x2, b);
  bf16x2 r = x * y;
  return __builtin_bit_cast(uint32_t, r);
}

__device__ __forceinline__ uint4 cvt8(float4 a, float4 b) {
  bf16x8 v;
  v[0] = (__bf16)a.x; v[1] = (__bf16)a.y; v[2] = (__bf16)a.z; v[3] = (__bf16)a.w;
  v[4] = (__bf16)b.x; v[5] = (__bf16)b.y; v[6] = (__bf16)b.z; v[7] = (__bf16)b.w;
  return __builtin_bit_cast(uint4, v);
}

// Prep: Wt = W transposed into MFMA B-fragment order (bf16, classes padded
// to 128 with zeros). 16B-chunk t: eo=t&3, c=(t>>2)&127, kc=t>>9:
//   Wt byte addr = kc*8192 + c*64 + eo*16  <->  W[c][kc*32 + eo*8 .. +7]
__global__ void prep_wt(const float* __restrict__ W, uint4* __restrict__ wt)
{
  const int nwt = NK32 * 128 * 4;      // 786,432
  int t = blockIdx.x * blockDim.x + threadIdx.x;
  if (t >= nwt) return;
  int eo = t & 3;
  int c  = (t >> 2) & 127;
  int kc = t >> 9;
  uint4 v = uint4{0u, 0u, 0u, 0u};
  if (c < NCLS) {
    const float4* p = (const float4*)(W + (size_t)c * KTOT + kc * 32 + eo * 8);
    v = cvt8(p[0], p[1]);
  }
  wt[t] = v;
}

// Fused on-the-fly-A GEMM, R11: NO LDS/barriers (R10 body), flat grid with
// XCD-aware slice swizzle, b1/b2 read f32 directly (cvt at kblk boundaries).
// logits[n,c] = sum_k A[n,k]*W[c,k]; A[n, kb*4096+i*64+j] = b1[n,kb,i]*b2[n,kb,j].
// MFMA 16x16x32 bf16 verified triple:
//   A: lane l holds A[m=l&15][k=(l>>4)*8+j]; B: W[c=l&15][k=(l>>4)*8+j]
//   D: lane l, reg r: col(c)=l&15, row(n)=(l>>4)*4+r
// Flat grid nslice*32. If G>0 (G=KS/8): slice s=(n&7)+8*((n>>3)%G) keeps each
// XCD's resident blocks on slices ≡ xcd (mod 8) -> Wt window stays in its L2.
__global__ __launch_bounds__(256, 2)
void bilinear_main(const float* __restrict__ b1g,
                   const float* __restrict__ b2g,
                   const char* __restrict__ Wt,
                   const float* __restrict__ biasg,
                   float* __restrict__ P,
                   float* __restrict__ outd,
                   int klen, int nslice, int G)
{
  const int tid  = threadIdx.x;
  const int w    = tid >> 6;
  const int l    = tid & 63;
  const int l15  = l & 15;
  const int quad = l >> 4;
  const int mhalf = w & 1;
  const int chalf = w >> 1;

  const int n = blockIdx.x;
  int s, bm;
  if (G > 0) { s = (n & 7) + 8 * ((n >> 3) % G); bm = (n >> 3) / G; }
  else       { s = n % nslice;                   bm = n / nslice; }
  const int k0 = s * klen;

  int nrow[4];
#pragma unroll
  for (int rt = 0; rt < 4; ++rt) nrow[rt] = bm * 128 + mhalf * 64 + rt * 16 + l15;

  // Lane-fixed Wt base for this block's k-range.
  const char* wtl = Wt + (size_t)(k0 >> 5) * 8192
                       + (chalf * 64 + l15) * 64 + quad * 16;

  floatx4 acc[4][4];
#pragma unroll
  for (int rt = 0; rt < 4; ++rt)
#pragma unroll
    for (int ct = 0; ct < 4; ++ct)
      acc[rt][ct] = floatx4{0.f, 0.f, 0.f, 0.f};

  uint4 b2c[4][2];   // bf16 b2[nrow[rt], kblk, kh*32+quad*8 .. +7]
  uint4 b1c[4];      // bf16 b1[nrow[rt], kblk, i0 .. i0+7]
  int cur_k = -1;
  const int nwin = klen >> 6;

  for (int gwin = 0; gwin < nwin; gwin += 8) {
    const int kap0 = k0 + (gwin << 6);
    const int kblk = kap0 >> 12;
    const int i0   = (kap0 >> 6) & 63;
    if (kblk != cur_k) {
      cur_k = kblk;
#pragma unroll
      for (int rt = 0; rt < 4; ++rt)
#pragma unroll
        for (int kh = 0; kh < 2; ++kh) {
          const float* p = b2g + (size_t)nrow[rt] * EMB +
                           kblk * 64 + kh * 32 + quad * 8;
          b2c[rt][kh] = cvt8(((const float4*)p)[0], ((const float4*)p)[1]);
        }
    }
#pragma unroll
    for (int rt = 0; rt < 4; ++rt) {
      const float* p = b1g + (size_t)nrow[rt] * EMB + kblk * 64 + i0;
      b1c[rt] = cvt8(((const float4*)p)[0], ((const float4*)p)[1]);
    }

#pragma unroll
    for (int ii = 0; ii < 8; ++ii) {
      const char* pw = wtl + (size_t)(gwin + ii) * 16384;

      // b1 scalar for this window, broadcast to a bf16 pair.
      uint32_t s2[4];
#pragma unroll
      for (int rt = 0; rt < 4; ++rt) {
        uint32_t d = (&b1c[rt].x)[ii >> 1];
        uint32_t h = (ii & 1) ? (d >> 16) : (d & 0xffffu);
        s2[rt] = h | (h << 16);
      }

#pragma unroll
      for (int kh = 0; kh < 2; ++kh) {
        // 4 coalesced B-fragment loads (16B/lane, 1KB-contig per ct)
        short8 wf[4];
#pragma unroll
        for (int ct = 0; ct < 4; ++ct)
          wf[ct] = __builtin_bit_cast(short8,
                     *(const uint4*)(pw + kh * 8192 + ct * 1024));
        // A fragments for this kh
        uint4 afr[4];
#pragma unroll
        for (int rt = 0; rt < 4; ++rt) {
          afr[rt].x = pkmul(s2[rt], b2c[rt][kh].x);
          afr[rt].y = pkmul(s2[rt], b2c[rt][kh].y);
          afr[rt].z = pkmul(s2[rt], b2c[rt][kh].z);
          afr[rt].w = pkmul(s2[rt], b2c[rt][kh].w);
        }
#pragma unroll
        for (int rt = 0; rt < 4; ++rt) {
          short8 af = __builtin_bit_cast(short8, afr[rt]);
#pragma unroll
          for (int ct = 0; ct < 4; ++ct)
            acc[rt][ct] = __builtin_amdgcn_mfma_f32_16x16x32_bf16(
                              af, wf[ct], acc[rt][ct], 0, 0, 0);
        }
      }
    }
  }

  // Epilogue. D: col(c)=l15, row(n)=quad*4+r within each 16x16 tile.
  if (P) {
    float* Pb = P + (size_t)s * OUT_ELEMS;
#pragma unroll
    for (int rt = 0; rt < 4; ++rt)
#pragma unroll
      for (int ct = 0; ct < 4; ++ct) {
        const int c = chalf * 64 + ct * 16 + l15;
        if (c < NCLS) {
#pragma unroll
          for (int r = 0; r < 4; ++r) {
            const int row = bm * 128 + mhalf * 64 + rt * 16 + quad * 4 + r;
            Pb[(size_t)row * NCLS + c] = acc[rt][ct][r];
          }
        }
      }
  } else {
#pragma unroll
    for (int rt = 0; rt < 4; ++rt)
#pragma unroll
      for (int ct = 0; ct < 4; ++ct) {
        const int c = chalf * 64 + ct * 16 + l15;
        if (c < NCLS) {
          const float bv = biasg[c];
#pragma unroll
          for (int r = 0; r < 4; ++r) {
            const int row = bm * 128 + mhalf * 64 + rt * 16 + quad * 4 + r;
            outd[(size_t)row * NCLS + c] = acc[rt][ct][r] + bv;
          }
        }
      }
  }
}

// Sum KS partial slices + f32 bias -> f32 output. float4-vectorized.
__global__ void reduce_bias(const float* __restrict__ P,
                            const float* __restrict__ biasg,
                            float* __restrict__ out, int KS)
{
  int i = blockIdx.x * blockDim.x + threadIdx.x;
  const int n4 = OUT_ELEMS / 4;           // 99328
  if (i >= n4) return;
  int c0 = (i * 4) % NCLS;
  int c1 = c0 + 1 == NCLS ? 0 : c0 + 1;
  int c2 = c1 + 1 == NCLS ? 0 : c1 + 1;
  int c3 = c2 + 1 == NCLS ? 0 : c2 + 1;
  float4 s;
  s.x = biasg[c0]; s.y = biasg[c1]; s.z = biasg[c2]; s.w = biasg[c3];
  const float4* P4 = (const float4*)P;
  for (int t = 0; t < KS; ++t) {
    float4 v = P4[(size_t)t * n4 + i];
    s.x += v.x; s.y += v.y; s.z += v.z; s.w += v.w;
  }
  ((float4*)out)[i] = s;
}

extern "C" void kernel_launch(void* const* d_in, const int* in_sizes, int n_in,
                              void* d_out, int out_size, void* d_ws, size_t ws_size,
                              hipStream_t stream) {
  const float* b1f = (const float*)d_in[0];   // [4096,768] f32
  const float* b2f = (const float*)d_in[1];   // [4096,768] f32
  const float* Wf  = (const float*)d_in[2];   // [97, 49152] f32
  const float* bbf = (const float*)d_in[3];   // [97] f32
  float* out = (float*)d_out;

  const size_t slice = (size_t)OUT_ELEMS * 4;   // 1,589,248
  // klen = KTOT/KS must be a multiple of 512: all candidates qualify.
  static const int cands[] = {32, 24, 16, 12, 8, 6, 4, 3, 2, 1};
  int KS = 0;
  for (int i = 0; i < 10; ++i)
    if (WT_BYTES + (size_t)cands[i] * slice <= ws_size) { KS = cands[i]; break; }

  uint4* Wt = (uint4*)d_ws;
  const int nwt = NK32 * 128 * 4;
  prep_wt<<<(nwt + 255) / 256, 256, 0, stream>>>(Wf, Wt);

  if (KS > 0) {
    float* P = (float*)((char*)d_ws + WT_BYTES);
    const int G = (KS % 8 == 0) ? KS / 8 : 0;
    bilinear_main<<<dim3(KS * 32), 256, 0, stream>>>(
        b1f, b2f, (const char*)Wt, bbf, P, nullptr, KTOT / KS, KS, G);
    reduce_bias<<<(OUT_ELEMS / 4 + 255) / 256, 256, 0, stream>>>(P, bbf, out, KS);
  } else {
    // Minimal-workspace fallback: single slice, direct f32 output.
    bilinear_main<<<dim3(32), 256, 0, stream>>>(
        b1f, b2f, (const char*)Wt, bbf, nullptr, out, KTOT, 1, 0);
  }
}